// Round 3
// baseline (153.543 us; speedup 1.0000x reference)
//
#include <hip/hip_runtime.h>

// Problem constants from setup_inputs(): shape (64, 16, 64, 64), fp32, kern=2.
#define N_ 64
#define C_ 16
#define H_ 64
#define W_ 64

// pair_kernel tiling (R5 inner structure — best measured): 4 i-rows x 8 j-rows
// per tile, D split into 16 chunks of 1024.
// tri sets (vaa, vbb): i-tile g (rows 4g..4g+3) needs j-tiles 0..(g>>1)
//   -> sum over g=0..15 of (g>>1)+1 = 72 tiles per set
// vab (full): 16 i-tiles x 8 j-tiles = 128 tiles. TILES = 72*2 + 128 = 272.
// R10: 512-thread blocks, each covering 2 adjacent chunks (half-block each).
#define TRI_TILES 72
#define TILES 272
#define DCHUNKS 16
#define PAIR_BLOCKS (TILES * (DCHUNKS / 2))   // 2176

// NUMERICS: ws stores var' = var * 2ln2. Then exp(-0.5 d^2/v)/sqrt(v)
//   = exp2(-(d*rsq(v'))^2) * rsq(v') * sqrt(2ln2);
// sqrt(2ln2)=1.1774100 folds into the per-block partial. 5 VALU + 2 transc/term.
#define TWO_LN2   1.3862943611198906f
#define SQRT_2LN2 1.1774100225154747f

// ws layout (floats): [0..Np) mu_a | [Np..2Np) var'_a | [2Np..3Np) mu_b |
// [3Np..4Np) var'_b | [4Np..4Np+PAIR_BLOCKS) per-block partials.
// R7 post-mortem: single-address atomicAdd tail serialized -> partials+reduce.
// R8 post-mortem: acc-shrink+prefetch -> VGPR 96, occ 18%, +4%: NOT latency-
//   fixable via registers; buying pipeline depth with VGPRs loses occupancy.
// R9 post-mortem: XCD-chunk pinning -> 55us (-21%). Natural R5 order (adjacent
//   blocks share a tile) beats chunk-slice L2 residency. Mapping reverted.
// R10: occupancy reads ~8 waves/CU vs 28 permitted by VGPR=68 -> limiter is
//   per-block scheduling, not registers. 512-thread blocks double waves per
//   scheduling unit at ZERO register cost. Inner loop identical to R5.

__global__ __launch_bounds__(256) void pool_kernel(
    const float* __restrict__ mu_a, const float* __restrict__ lv_a,
    const float* __restrict__ mu_b, const float* __restrict__ lv_b,
    const int* __restrict__ kern_p, float* __restrict__ ws) {
    const int k = kern_p[0];
    const float LOG2E = 1.44269504088896f;

    if (k == 2) {
        // Fast path: 4 contiguous pooled outputs per thread, all-shift indexing.
        const int Np = (N_ * C_ * H_ * W_) >> 2;  // 1048576
        const int Q  = Np >> 2;                   // 262144 quads per array
        const int total = 4 * Q;
        for (int g = blockIdx.x * blockDim.x + threadIdx.x; g < total;
             g += gridDim.x * blockDim.x) {
            const int a  = g >> 18;               // log2(Q) = 18
            const int r4 = g & (Q - 1);
            const int pw4 = (r4 & 7) << 2;        // Wp=32 -> 8 quads/row
            const int t   = r4 >> 3;
            const int ph  = t & 31;               // Hp=32
            const int nc  = t >> 5;
            const float* src = (a == 0) ? mu_a : (a == 1) ? lv_a : (a == 2) ? mu_b : lv_b;
            const bool is_var = (a & 1);
            const float* p0 = src + nc * (H_ * W_) + (ph * 2) * W_ + pw4 * 2;
            float4 r0a = *(const float4*)(p0);
            float4 r0b = *(const float4*)(p0 + 4);
            float4 r1a = *(const float4*)(p0 + W_);
            float4 r1b = *(const float4*)(p0 + W_ + 4);
            float o0, o1, o2, o3;
            if (is_var) {
#define E_(x) __builtin_amdgcn_exp2f((x) * LOG2E)
                o0 = E_(r0a.x) + E_(r0a.y) + E_(r1a.x) + E_(r1a.y);
                o1 = E_(r0a.z) + E_(r0a.w) + E_(r1a.z) + E_(r1a.w);
                o2 = E_(r0b.x) + E_(r0b.y) + E_(r1b.x) + E_(r1b.y);
                o3 = E_(r0b.z) + E_(r0b.w) + E_(r1b.z) + E_(r1b.w);
#undef E_
                const float s = (1.0f / 16.0f) * TWO_LN2;  // 1/k^4 * 2ln2
                o0 *= s; o1 *= s; o2 *= s; o3 *= s;
            } else {
                o0 = r0a.x + r0a.y + r1a.x + r1a.y;
                o1 = r0a.z + r0a.w + r1a.z + r1a.w;
                o2 = r0b.x + r0b.y + r1b.x + r1b.y;
                o3 = r0b.z + r0b.w + r1b.z + r1b.w;
                const float s = 0.25f;            // 1/k^2
                o0 *= s; o1 *= s; o2 *= s; o3 *= s;
            }
            *(float4*)(ws + (size_t)a * Np + (size_t)r4 * 4) = make_float4(o0, o1, o2, o3);
        }
    } else {
        // Generic fallback (any k dividing 64).
        const int Hp = H_ / k, Wp = W_ / k;
        const int Np = N_ * C_ * Hp * Wp;
        const float inv_k2 = 1.0f / (float)(k * k);
        const float inv_k4 = inv_k2 * inv_k2 * TWO_LN2;   // fold var pre-scale
        const int total = 4 * Np;
        for (int p = blockIdx.x * blockDim.x + threadIdx.x; p < total;
             p += gridDim.x * blockDim.x) {
            const int a  = p / Np;
            const int r  = p - a * Np;
            const int pw = r % Wp;
            const int t1 = r / Wp;
            const int ph = t1 % Hp;
            const int nc = t1 / Hp;
            const float* src = (a == 0) ? mu_a : (a == 1) ? lv_a : (a == 2) ? mu_b : lv_b;
            const bool is_var = (a & 1);
            const int base = nc * (H_ * W_) + (ph * k) * W_ + (pw * k);
            float s = 0.0f;
            for (int dy = 0; dy < k; ++dy) {
                const float* row = src + base + dy * W_;
                for (int dx = 0; dx < k; ++dx) {
                    float x = row[dx];
                    s += is_var ? __builtin_amdgcn_exp2f(x * LOG2E) : x;
                }
            }
            ws[(size_t)a * Np + r] = s * (is_var ? inv_k4 : inv_k2);
        }
    }
}

// R10: 512 threads/block, 2 adjacent chunks per block (threadIdx>>8 picks the
// half). Block->tile mapping keeps R5's order: consecutive blocks share tile t
// (8 chunk-pair blocks per tile) -> same L2 locality that beat R9's swizzle.
// Inner loop byte-identical to R5. No min-waves clause (R3: spills).
__global__ __launch_bounds__(512) void pair_kernel(float* __restrict__ ws,
                                                   const int* __restrict__ kern_p) {
    const int k = kern_p[0];
    const int D  = C_ * (H_ / k) * (W_ / k);
    const int Np = N_ * D;

    const float* mu_a = ws;
    const float* va   = ws + (size_t)Np;
    const float* mu_b = ws + (size_t)2 * Np;
    const float* vb   = ws + (size_t)3 * Np;
    float* partials   = ws + (size_t)4 * Np;

    // ---- decode block -> (tile, chunk-pair); half-block picks the chunk ----
    const int cp = blockIdx.x & 7;               // chunk pair 0..7
    const int t  = blockIdx.x >> 3;              // tile 0..271
    const int c  = (cp << 1) | ((int)threadIdx.x >> 8);   // chunk 0..15
    const int tidc = (int)threadIdx.x & 255;     // lane within the chunk

    int set, it, jt;
    if (t >= 2 * TRI_TILES) {
        set = 2;
        const int tt = t - 2 * TRI_TILES;
        it = tt >> 3;
        jt = tt & 7;
    } else {
        set = (t >= TRI_TILES) ? 1 : 0;
        const int tt = set ? (t - TRI_TILES) : t;
        int g = 0, cum = 0;
        while (cum + (g >> 1) + 1 <= tt) { cum += (g >> 1) + 1; ++g; }
        it = g;
        jt = tt - cum;
    }
    const int i0 = it * 4, j0 = jt * 8;

    const float *mu1, *v1, *mu2, *v2;
    if (set == 0)      { mu1 = mu2 = mu_a; v1 = v2 = va; }
    else if (set == 1) { mu1 = mu2 = mu_b; v1 = v2 = vb; }
    else               { mu1 = mu_a; v1 = va; mu2 = mu_b; v2 = vb; }

#define TERM(acc, mx1, sx1, mx2, sx2)                                  \
    {                                                                  \
        float v  = (sx1) + (sx2);                                      \
        float rs = __builtin_amdgcn_rsqf(v);                           \
        float d  = (mx1) - (mx2);                                      \
        float t_ = d * rs;                                             \
        float e  = __builtin_amdgcn_exp2f(-(t_ * t_));                 \
        acc = fmaf(e, rs, acc);                                        \
    }

    float accs[4][8];
    #pragma unroll
    for (int ir = 0; ir < 4; ++ir)
        #pragma unroll
        for (int j8 = 0; j8 < 8; ++j8) accs[ir][j8] = 0.0f;

    if (D == 16384) {
        // Fast path: chunk = 1024 elems = 256 threads x 1 float4.
        const int base = (c << 10) + (tidc << 2);
        float4 im[4], iv[4];
        #pragma unroll
        for (int ir = 0; ir < 4; ++ir) {
            im[ir] = *(const float4*)(mu1 + (size_t)(i0 + ir) * 16384 + base);
            iv[ir] = *(const float4*)(v1  + (size_t)(i0 + ir) * 16384 + base);
        }
        #pragma unroll
        for (int j8 = 0; j8 < 8; ++j8) {
            const float4 jm = *(const float4*)(mu2 + (size_t)(j0 + j8) * 16384 + base);
            const float4 jv = *(const float4*)(v2  + (size_t)(j0 + j8) * 16384 + base);
            #pragma unroll
            for (int ir = 0; ir < 4; ++ir) {
                TERM(accs[ir][j8], im[ir].x, iv[ir].x, jm.x, jv.x)
                TERM(accs[ir][j8], im[ir].y, iv[ir].y, jm.y, jv.y)
                TERM(accs[ir][j8], im[ir].z, iv[ir].z, jm.z, jv.z)
                TERM(accs[ir][j8], im[ir].w, iv[ir].w, jm.w, jv.w)
            }
        }
    } else {
        // Generic fallback: chunk c covers [c*D/16, (c+1)*D/16), scalar loads.
        const int cs = D / DCHUNKS;
        const int lo = c * cs, hi = lo + cs;
        for (int e = lo + tidc; e < hi; e += 256) {
            #pragma unroll
            for (int j8 = 0; j8 < 8; ++j8) {
                const float mj = mu2[(size_t)(j0 + j8) * D + e];
                const float vj = v2 [(size_t)(j0 + j8) * D + e];
                #pragma unroll
                for (int ir = 0; ir < 4; ++ir) {
                    const float mi = mu1[(size_t)(i0 + ir) * D + e];
                    const float vi = v1 [(size_t)(i0 + ir) * D + e];
                    TERM(accs[ir][j8], mi, vi, mj, vj)
                }
            }
        }
    }
#undef TERM

    float tot = 0.0f;
    #pragma unroll
    for (int ir = 0; ir < 4; ++ir) {
        #pragma unroll
        for (int j8 = 0; j8 < 8; ++j8) {
            float w;
            if (set == 2) w = -2.0f;
            else {
                const int ii = i0 + ir, jj = j0 + j8;
                w = (jj > ii) ? 0.0f : (jj == ii) ? 1.0f : 2.0f;
            }
            tot = fmaf(w, accs[ir][j8], tot);
        }
    }
    tot *= SQRT_2LN2;   // fold the var'-prescale correction once

    for (int off = 32; off > 0; off >>= 1)
        tot += __shfl_down(tot, off, 64);
    __shared__ float wsum[8];
    const int lane = threadIdx.x & 63;
    const int wid  = threadIdx.x >> 6;           // 8 waves
    if (lane == 0) wsum[wid] = tot;
    __syncthreads();
    if (threadIdx.x == 0) {
        float s = 0.0f;
        #pragma unroll
        for (int wq = 0; wq < 8; ++wq) s += wsum[wq];
        partials[blockIdx.x] = s;
    }
}

// Single block: sum the PAIR_BLOCKS partials into out[0].
__global__ __launch_bounds__(256) void reduce_kernel(const float* __restrict__ ws,
                                                     const int* __restrict__ kern_p,
                                                     float* __restrict__ out) {
    const int k = kern_p[0];
    const int D  = C_ * (H_ / k) * (W_ / k);
    const int Np = N_ * D;
    const float* partials = ws + (size_t)4 * Np;

    float s = 0.0f;
    for (int p = threadIdx.x; p < PAIR_BLOCKS; p += 256) s += partials[p];
    for (int off = 32; off > 0; off >>= 1)
        s += __shfl_down(s, off, 64);
    __shared__ float wsum[4];
    const int lane = threadIdx.x & 63;
    const int wid  = threadIdx.x >> 6;
    if (lane == 0) wsum[wid] = s;
    __syncthreads();
    if (threadIdx.x == 0) out[0] = wsum[0] + wsum[1] + wsum[2] + wsum[3];
}

extern "C" void kernel_launch(void* const* d_in, const int* in_sizes, int n_in,
                              void* d_out, int out_size, void* d_ws, size_t ws_size,
                              hipStream_t stream) {
    const float* mu_a = (const float*)d_in[0];
    const float* lv_a = (const float*)d_in[1];
    const float* mu_b = (const float*)d_in[2];
    const float* lv_b = (const float*)d_in[3];
    const int*   kern = (const int*)d_in[4];
    float* out = (float*)d_out;
    float* ws  = (float*)d_ws;

    pool_kernel<<<4096, 256, 0, stream>>>(mu_a, lv_a, mu_b, lv_b, kern, ws);
    pair_kernel<<<PAIR_BLOCKS, 512, 0, stream>>>(ws, kern);
    reduce_kernel<<<1, 256, 0, stream>>>(ws, kern, out);
}

// Round 4
// 151.352 us; speedup vs baseline: 1.0145x; 1.0145x over previous
//
#include <hip/hip_runtime.h>

// Problem constants from setup_inputs(): shape (64, 16, 64, 64), fp32, kern=2.
#define N_ 64
#define C_ 16
#define H_ 64
#define W_ 64

// R11 tiling: 8 i-rows x 8 j-rows per tile, D split into 16 chunks of 1024.
// Rationale: R9/R10 proved pair_kernel is cache-BW bound (~9.4 TB/s of L2/LLC
// reads). 8x8 reads 16 rows per 64 pairs (0.25 rows/pair) vs R5's 4x8 at
// 12/32 (0.375) -> total read traffic 428 -> 278 MB.
// tri sets (vaa, vbb): i-tile g (rows 8g..8g+7) needs j-tiles 0..g
//   -> sum over g=0..7 of (g+1) = 36 tiles per set. Diagonal tiles (jt==it)
//   have i0==j0 so per-pair weights are compile-time; w=0 terms are skipped.
// vab (full): 8 i-tiles x 8 j-tiles = 64 tiles. TILES = 36*2 + 64 = 136.
#define TRI_TILES 36
#define TILES 136
#define DCHUNKS 16
#define PAIR_BLOCKS (TILES * DCHUNKS)   // 2176

// NUMERICS: ws stores var' = var * 2ln2. Then exp(-0.5 d^2/v)/sqrt(v)
//   = exp2(-(d*rsq(v'))^2) * rsq(v') * sqrt(2ln2);
// sqrt(2ln2)=1.1774100 folds into the per-block partial. 5 VALU + 2 transc/term.
#define TWO_LN2   1.3862943611198906f
#define SQRT_2LN2 1.1774100225154747f

// ws layout (floats): [0..Np) mu_a | [Np..2Np) var'_a | [2Np..3Np) mu_b |
// [3Np..4Np) var'_b | [4Np..4Np+PAIR_BLOCKS) per-block partials.
// Post-mortems:
// R7: single-address atomicAdd tail serialized -> partials + 1-block reduce.
// R8: acc-shrink+manual prefetch, same traffic -> VGPR 96, occ 18%, +4%.
//     Registers spent WITHOUT a traffic cut lose.
// R9: XCD-chunk pinning, same instrs+traffic -> +21%. Mapping-sensitive =>
//     not compute-bound; natural order has the better locality.
// R10: 512-thread blocks, same order -> +23%; live footprint 25->49MB diluted
//     LLC locality. Conclusion: BW-bound at ~9.4 TB/s => R11 cuts traffic.

__global__ __launch_bounds__(256) void pool_kernel(
    const float* __restrict__ mu_a, const float* __restrict__ lv_a,
    const float* __restrict__ mu_b, const float* __restrict__ lv_b,
    const int* __restrict__ kern_p, float* __restrict__ ws) {
    const int k = kern_p[0];
    const float LOG2E = 1.44269504088896f;

    if (k == 2) {
        // Fast path: 4 contiguous pooled outputs per thread, all-shift indexing.
        const int Np = (N_ * C_ * H_ * W_) >> 2;  // 1048576
        const int Q  = Np >> 2;                   // 262144 quads per array
        const int total = 4 * Q;
        for (int g = blockIdx.x * blockDim.x + threadIdx.x; g < total;
             g += gridDim.x * blockDim.x) {
            const int a  = g >> 18;               // log2(Q) = 18
            const int r4 = g & (Q - 1);
            const int pw4 = (r4 & 7) << 2;        // Wp=32 -> 8 quads/row
            const int t   = r4 >> 3;
            const int ph  = t & 31;               // Hp=32
            const int nc  = t >> 5;
            const float* src = (a == 0) ? mu_a : (a == 1) ? lv_a : (a == 2) ? mu_b : lv_b;
            const bool is_var = (a & 1);
            const float* p0 = src + nc * (H_ * W_) + (ph * 2) * W_ + pw4 * 2;
            float4 r0a = *(const float4*)(p0);
            float4 r0b = *(const float4*)(p0 + 4);
            float4 r1a = *(const float4*)(p0 + W_);
            float4 r1b = *(const float4*)(p0 + W_ + 4);
            float o0, o1, o2, o3;
            if (is_var) {
#define E_(x) __builtin_amdgcn_exp2f((x) * LOG2E)
                o0 = E_(r0a.x) + E_(r0a.y) + E_(r1a.x) + E_(r1a.y);
                o1 = E_(r0a.z) + E_(r0a.w) + E_(r1a.z) + E_(r1a.w);
                o2 = E_(r0b.x) + E_(r0b.y) + E_(r1b.x) + E_(r1b.y);
                o3 = E_(r0b.z) + E_(r0b.w) + E_(r1b.z) + E_(r1b.w);
#undef E_
                const float s = (1.0f / 16.0f) * TWO_LN2;  // 1/k^4 * 2ln2
                o0 *= s; o1 *= s; o2 *= s; o3 *= s;
            } else {
                o0 = r0a.x + r0a.y + r1a.x + r1a.y;
                o1 = r0a.z + r0a.w + r1a.z + r1a.w;
                o2 = r0b.x + r0b.y + r1b.x + r1b.y;
                o3 = r0b.z + r0b.w + r1b.z + r1b.w;
                const float s = 0.25f;            // 1/k^2
                o0 *= s; o1 *= s; o2 *= s; o3 *= s;
            }
            *(float4*)(ws + (size_t)a * Np + (size_t)r4 * 4) = make_float4(o0, o1, o2, o3);
        }
    } else {
        // Generic fallback (any k dividing 64).
        const int Hp = H_ / k, Wp = W_ / k;
        const int Np = N_ * C_ * Hp * Wp;
        const float inv_k2 = 1.0f / (float)(k * k);
        const float inv_k4 = inv_k2 * inv_k2 * TWO_LN2;   // fold var pre-scale
        const int total = 4 * Np;
        for (int p = blockIdx.x * blockDim.x + threadIdx.x; p < total;
             p += gridDim.x * blockDim.x) {
            const int a  = p / Np;
            const int r  = p - a * Np;
            const int pw = r % Wp;
            const int t1 = r / Wp;
            const int ph = t1 % Hp;
            const int nc = t1 / Hp;
            const float* src = (a == 0) ? mu_a : (a == 1) ? lv_a : (a == 2) ? mu_b : lv_b;
            const bool is_var = (a & 1);
            const int base = nc * (H_ * W_) + (ph * k) * W_ + (pw * k);
            float s = 0.0f;
            for (int dy = 0; dy < k; ++dy) {
                const float* row = src + base + dy * W_;
                for (int dx = 0; dx < k; ++dx) {
                    float x = row[dx];
                    s += is_var ? __builtin_amdgcn_exp2f(x * LOG2E) : x;
                }
            }
            ws[(size_t)a * Np + r] = s * (is_var ? inv_k4 : inv_k2);
        }
    }
}

// R11 pair: 256 threads, 8x8 tile, chunk = 1024 elems = thread-float4.
// Natural block order kept (consecutive blocks = 16 chunks of one tile) —
// the locality R9 proved essential. Collapsed accumulators acc[ir][component]
// (32 regs); off-diag tri tiles are uniformly w=2, vab w=-2 (applied once at
// the end); diagonal tiles have i0==j0 so weights are compile-time and the
// jj>ii (w=0) terms are skipped. NOTE: no min-waves clause (R3: spills).
__global__ __launch_bounds__(256) void pair_kernel(float* __restrict__ ws,
                                                   const int* __restrict__ kern_p) {
    const int k = kern_p[0];
    const int D  = C_ * (H_ / k) * (W_ / k);
    const int Np = N_ * D;

    const float* mu_a = ws;
    const float* va   = ws + (size_t)Np;
    const float* mu_b = ws + (size_t)2 * Np;
    const float* vb   = ws + (size_t)3 * Np;
    float* partials   = ws + (size_t)4 * Np;

    // ---- decode block -> (tile, chunk) ----
    const int c = blockIdx.x & (DCHUNKS - 1);
    const int t = blockIdx.x >> 4;           // DCHUNKS == 16
    int set, it, jt;
    if (t >= 2 * TRI_TILES) {
        set = 2;
        const int tt = t - 2 * TRI_TILES;
        it = tt >> 3;
        jt = tt & 7;
    } else {
        set = (t >= TRI_TILES) ? 1 : 0;
        const int tt = set ? (t - TRI_TILES) : t;
        int g = 0, cum = 0;
        while (cum + g + 1 <= tt) { cum += g + 1; ++g; }
        it = g;
        jt = tt - cum;
    }
    const int i0 = it * 8, j0 = jt * 8;

    const float *mu1, *v1, *mu2, *v2;
    if (set == 0)      { mu1 = mu2 = mu_a; v1 = v2 = va; }
    else if (set == 1) { mu1 = mu2 = mu_b; v1 = v2 = vb; }
    else               { mu1 = mu_a; v1 = va; mu2 = mu_b; v2 = vb; }

    const bool diag = (set < 2) && (it == jt);
    const float wU  = (set == 2) ? -2.0f : 2.0f;   // uniform-tile weight

#define TERM(acc, mx1, sx1, mx2, sx2)                                  \
    {                                                                  \
        float v  = (sx1) + (sx2);                                      \
        float rs = __builtin_amdgcn_rsqf(v);                           \
        float d  = (mx1) - (mx2);                                      \
        float t_ = d * rs;                                             \
        float e  = __builtin_amdgcn_exp2f(-(t_ * t_));                 \
        acc = fmaf(e, rs, acc);                                        \
    }
#define TERMW(acc, mx1, sx1, mx2, sx2, w)                              \
    {                                                                  \
        float v  = (sx1) + (sx2);                                      \
        float rs = __builtin_amdgcn_rsqf(v);                           \
        float d  = (mx1) - (mx2);                                      \
        float t_ = d * rs;                                             \
        float e  = __builtin_amdgcn_exp2f(-(t_ * t_));                 \
        acc = fmaf((w), e * rs, acc);                                  \
    }

    // Collapsed accumulators: [i-row][float4 component]. Dep distance between
    // fmas into the same acc >= 32 terms in the fast path — no latency chain.
    float acc[8][4];
    #pragma unroll
    for (int ir = 0; ir < 8; ++ir)
        #pragma unroll
        for (int q = 0; q < 4; ++q) acc[ir][q] = 0.0f;

    float wmul = 1.0f;   // end-applied weight (uniform fast path only)

    if (D == 16384) {
        const int base = (c << 10) + ((int)threadIdx.x << 2);
        float4 im[8], iv[8];
        #pragma unroll
        for (int ir = 0; ir < 8; ++ir) {
            im[ir] = *(const float4*)(mu1 + (size_t)(i0 + ir) * 16384 + base);
            iv[ir] = *(const float4*)(v1  + (size_t)(i0 + ir) * 16384 + base);
        }
        if (!diag) {
            wmul = wU;
            #pragma unroll
            for (int j8 = 0; j8 < 8; ++j8) {
                const float4 jm = *(const float4*)(mu2 + (size_t)(j0 + j8) * 16384 + base);
                const float4 jv = *(const float4*)(v2  + (size_t)(j0 + j8) * 16384 + base);
                #pragma unroll
                for (int ir = 0; ir < 8; ++ir) {
                    TERM(acc[ir][0], im[ir].x, iv[ir].x, jm.x, jv.x)
                    TERM(acc[ir][1], im[ir].y, iv[ir].y, jm.y, jv.y)
                    TERM(acc[ir][2], im[ir].z, iv[ir].z, jm.z, jv.z)
                    TERM(acc[ir][3], im[ir].w, iv[ir].w, jm.w, jv.w)
                }
            }
        } else {
            // Diagonal tile: i0 == j0, weights compile-time. Skip jj>ii (w=0),
            // w=1 on the diagonal, w=2 below it.
            #pragma unroll
            for (int j8 = 0; j8 < 8; ++j8) {
                const float4 jm = *(const float4*)(mu2 + (size_t)(j0 + j8) * 16384 + base);
                const float4 jv = *(const float4*)(v2  + (size_t)(j0 + j8) * 16384 + base);
                #pragma unroll
                for (int ir = 0; ir < 8; ++ir) {
                    if (ir < j8) continue;        // w = 0 (compile-time pruned)
                    if (ir == j8) {
                        TERM(acc[ir][0], im[ir].x, iv[ir].x, jm.x, jv.x)
                        TERM(acc[ir][1], im[ir].y, iv[ir].y, jm.y, jv.y)
                        TERM(acc[ir][2], im[ir].z, iv[ir].z, jm.z, jv.z)
                        TERM(acc[ir][3], im[ir].w, iv[ir].w, jm.w, jv.w)
                    } else {
                        TERMW(acc[ir][0], im[ir].x, iv[ir].x, jm.x, jv.x, 2.0f)
                        TERMW(acc[ir][1], im[ir].y, iv[ir].y, jm.y, jv.y, 2.0f)
                        TERMW(acc[ir][2], im[ir].z, iv[ir].z, jm.z, jv.z, 2.0f)
                        TERMW(acc[ir][3], im[ir].w, iv[ir].w, jm.w, jv.w, 2.0f)
                    }
                }
            }
        }
    } else {
        // Generic fallback: chunk c covers [c*D/16, (c+1)*D/16), scalar loads,
        // runtime weights folded per term.
        const int cs = D / DCHUNKS;
        const int lo = c * cs, hi = lo + cs;
        for (int e = lo + (int)threadIdx.x; e < hi; e += 256) {
            #pragma unroll
            for (int j8 = 0; j8 < 8; ++j8) {
                const int jj = j0 + j8;
                const float mj = mu2[(size_t)jj * D + e];
                const float vj = v2 [(size_t)jj * D + e];
                #pragma unroll
                for (int ir = 0; ir < 8; ++ir) {
                    const int ii = i0 + ir;
                    const float w = (set == 2) ? -2.0f
                                  : (jj > ii) ? 0.0f : (jj == ii) ? 1.0f : 2.0f;
                    const float mi = mu1[(size_t)ii * D + e];
                    const float vi = v1 [(size_t)ii * D + e];
                    TERMW(acc[ir][j8 & 3], mi, vi, mj, vj, w)
                }
            }
        }
    }
#undef TERM
#undef TERMW

    float tot = 0.0f;
    #pragma unroll
    for (int ir = 0; ir < 8; ++ir)
        #pragma unroll
        for (int q = 0; q < 4; ++q) tot += acc[ir][q];
    tot *= wmul * SQRT_2LN2;   // uniform weight + var'-prescale correction

    for (int off = 32; off > 0; off >>= 1)
        tot += __shfl_down(tot, off, 64);
    __shared__ float wsum[4];
    const int lane = threadIdx.x & 63;
    const int wid  = threadIdx.x >> 6;
    if (lane == 0) wsum[wid] = tot;
    __syncthreads();
    if (threadIdx.x == 0) {
        partials[blockIdx.x] = wsum[0] + wsum[1] + wsum[2] + wsum[3];
    }
}

// Single block: sum the PAIR_BLOCKS partials into out[0].
__global__ __launch_bounds__(256) void reduce_kernel(const float* __restrict__ ws,
                                                     const int* __restrict__ kern_p,
                                                     float* __restrict__ out) {
    const int k = kern_p[0];
    const int D  = C_ * (H_ / k) * (W_ / k);
    const int Np = N_ * D;
    const float* partials = ws + (size_t)4 * Np;

    float s = 0.0f;
    for (int p = threadIdx.x; p < PAIR_BLOCKS; p += 256) s += partials[p];
    for (int off = 32; off > 0; off >>= 1)
        s += __shfl_down(s, off, 64);
    __shared__ float wsum[4];
    const int lane = threadIdx.x & 63;
    const int wid  = threadIdx.x >> 6;
    if (lane == 0) wsum[wid] = s;
    __syncthreads();
    if (threadIdx.x == 0) out[0] = wsum[0] + wsum[1] + wsum[2] + wsum[3];
}

extern "C" void kernel_launch(void* const* d_in, const int* in_sizes, int n_in,
                              void* d_out, int out_size, void* d_ws, size_t ws_size,
                              hipStream_t stream) {
    const float* mu_a = (const float*)d_in[0];
    const float* lv_a = (const float*)d_in[1];
    const float* mu_b = (const float*)d_in[2];
    const float* lv_b = (const float*)d_in[3];
    const int*   kern = (const int*)d_in[4];
    float* out = (float*)d_out;
    float* ws  = (float*)d_ws;

    pool_kernel<<<4096, 256, 0, stream>>>(mu_a, lv_a, mu_b, lv_b, kern, ws);
    pair_kernel<<<PAIR_BLOCKS, 256, 0, stream>>>(ws, kern);
    reduce_kernel<<<1, 256, 0, stream>>>(ws, kern, out);
}

// Round 5
// 136.151 us; speedup vs baseline: 1.1277x; 1.1117x over previous
//
#include <hip/hip_runtime.h>

// Problem constants from setup_inputs(): shape (64, 16, 64, 64), fp32, kern=2.
#define N_ 64
#define C_ 16
#define H_ 64
#define W_ 64

// pair_kernel tiling: R5 structure EXACTLY (best measured 45.6us): 4 i-rows x
// 8 j-rows per tile, D split into 16 chunks of 1024, natural block order.
// tri sets (vaa, vbb): i-tile g needs j-tiles 0..(g>>1) -> 72 tiles/set.
// vab (full): 16 x 8 = 128 tiles. TILES = 72*2 + 128 = 272.
#define TRI_TILES 72
#define TILES 272
#define DCHUNKS 16
#define PAIR_BLOCKS (TILES * DCHUNKS)   // 4352

// NUMERICS: ws stores var' = var * 2ln2. exp(-0.5 d^2/v)/sqrt(v)
//   = exp2(-(d*rsq(v'))^2) * rsq(v') * sqrt(2ln2). 5 VALU + 2 transc/term.
#define TWO_LN2   1.3862943611198906f
#define SQRT_2LN2 1.1774100225154747f

// ws layout (floats): [0..Np) mu_a | [Np..2Np) var'_a | [2Np..3Np) mu_b |
// [3Np..4Np) var'_b | [4Np..4Np+PAIR_BLOCKS) per-block partials.
// Post-mortem ledger:
// R7: atomicAdd tail serialized -> partials + 1-block reduce.
// R8: prefetch+small accs -> VGPR 96, occ 18%, +4%. Register spend w/o
//     traffic gain loses occupancy.
// R9: XCD pinning -> +21%. Natural order's locality wins; mapping-sensitive.
// R10: 512-thread blocks -> +23%. Footprint dilution.
// R11: 8x8 tile (traffic 418->278MB) -> 53.5us SLOWER; eff BW fell 9.4->5.2
//     TB/s as occ fell 26->9.4%. CONCLUSION: memory system is LATENCY-bound;
//     achieved BW ~ resident waves. Minimize persistent VGPRs at fixed R5
//     memory pattern.
// R12 (this): (a) kill the 32-reg accs[4][8] — fold tile weights at the end
//     of each j8 iteration (uniform tiles: once per block); persistent acc
//     state 32 -> ~9 regs. (b) packed fp32 (ext_vector f32x2 -> v_pk_*) for
//     the TERM chain: full-rate VALU 5 -> 2.5 instr/term. Memory pattern,
//     grid, mapping identical to R5.

typedef __attribute__((ext_vector_type(2))) float f32x2;

__global__ __launch_bounds__(256) void pool_kernel(
    const float* __restrict__ mu_a, const float* __restrict__ lv_a,
    const float* __restrict__ mu_b, const float* __restrict__ lv_b,
    const int* __restrict__ kern_p, float* __restrict__ ws) {
    const int k = kern_p[0];
    const float LOG2E = 1.44269504088896f;

    if (k == 2) {
        // Fast path: 4 contiguous pooled outputs per thread, all-shift indexing.
        const int Np = (N_ * C_ * H_ * W_) >> 2;  // 1048576
        const int Q  = Np >> 2;                   // 262144 quads per array
        const int total = 4 * Q;
        for (int g = blockIdx.x * blockDim.x + threadIdx.x; g < total;
             g += gridDim.x * blockDim.x) {
            const int a  = g >> 18;               // log2(Q) = 18
            const int r4 = g & (Q - 1);
            const int pw4 = (r4 & 7) << 2;        // Wp=32 -> 8 quads/row
            const int t   = r4 >> 3;
            const int ph  = t & 31;               // Hp=32
            const int nc  = t >> 5;
            const float* src = (a == 0) ? mu_a : (a == 1) ? lv_a : (a == 2) ? mu_b : lv_b;
            const bool is_var = (a & 1);
            const float* p0 = src + nc * (H_ * W_) + (ph * 2) * W_ + pw4 * 2;
            float4 r0a = *(const float4*)(p0);
            float4 r0b = *(const float4*)(p0 + 4);
            float4 r1a = *(const float4*)(p0 + W_);
            float4 r1b = *(const float4*)(p0 + W_ + 4);
            float o0, o1, o2, o3;
            if (is_var) {
#define E_(x) __builtin_amdgcn_exp2f((x) * LOG2E)
                o0 = E_(r0a.x) + E_(r0a.y) + E_(r1a.x) + E_(r1a.y);
                o1 = E_(r0a.z) + E_(r0a.w) + E_(r1a.z) + E_(r1a.w);
                o2 = E_(r0b.x) + E_(r0b.y) + E_(r1b.x) + E_(r1b.y);
                o3 = E_(r0b.z) + E_(r0b.w) + E_(r1b.z) + E_(r1b.w);
#undef E_
                const float s = (1.0f / 16.0f) * TWO_LN2;  // 1/k^4 * 2ln2
                o0 *= s; o1 *= s; o2 *= s; o3 *= s;
            } else {
                o0 = r0a.x + r0a.y + r1a.x + r1a.y;
                o1 = r0a.z + r0a.w + r1a.z + r1a.w;
                o2 = r0b.x + r0b.y + r1b.x + r1b.y;
                o3 = r0b.z + r0b.w + r1b.z + r1b.w;
                const float s = 0.25f;            // 1/k^2
                o0 *= s; o1 *= s; o2 *= s; o3 *= s;
            }
            *(float4*)(ws + (size_t)a * Np + (size_t)r4 * 4) = make_float4(o0, o1, o2, o3);
        }
    } else {
        // Generic fallback (any k dividing 64).
        const int Hp = H_ / k, Wp = W_ / k;
        const int Np = N_ * C_ * Hp * Wp;
        const float inv_k2 = 1.0f / (float)(k * k);
        const float inv_k4 = inv_k2 * inv_k2 * TWO_LN2;   // fold var pre-scale
        const int total = 4 * Np;
        for (int p = blockIdx.x * blockDim.x + threadIdx.x; p < total;
             p += gridDim.x * blockDim.x) {
            const int a  = p / Np;
            const int r  = p - a * Np;
            const int pw = r % Wp;
            const int t1 = r / Wp;
            const int ph = t1 % Hp;
            const int nc = t1 / Hp;
            const float* src = (a == 0) ? mu_a : (a == 1) ? lv_a : (a == 2) ? mu_b : lv_b;
            const bool is_var = (a & 1);
            const int base = nc * (H_ * W_) + (ph * k) * W_ + (pw * k);
            float s = 0.0f;
            for (int dy = 0; dy < k; ++dy) {
                const float* row = src + base + dy * W_;
                for (int dx = 0; dx < k; ++dx) {
                    float x = row[dx];
                    s += is_var ? __builtin_amdgcn_exp2f(x * LOG2E) : x;
                }
            }
            ws[(size_t)a * Np + r] = s * (is_var ? inv_k4 : inv_k2);
        }
    }
}

// Packed 2-term Gaussian chain: v_pk_add / v_pk_mul / v_pk_fma on f32x2,
// scalar rsq/exp2 per component (no packed transcendentals exist).
#define TERM2(ACC, IM, IV, JM, JV)                                     \
    {                                                                  \
        f32x2 v_  = (IV) + (JV);                                       \
        f32x2 rs_; rs_.x = __builtin_amdgcn_rsqf(v_.x);                \
                   rs_.y = __builtin_amdgcn_rsqf(v_.y);                \
        f32x2 d_  = (IM) - (JM);                                       \
        f32x2 t_  = d_ * rs_;                                          \
        f32x2 nt_ = -t_ * t_;                                          \
        f32x2 e_; e_.x = __builtin_amdgcn_exp2f(nt_.x);                \
                  e_.y = __builtin_amdgcn_exp2f(nt_.y);                \
        ACC += e_ * rs_;                                               \
    }

__global__ __launch_bounds__(256) void pair_kernel(float* __restrict__ ws,
                                                   const int* __restrict__ kern_p) {
    const int k = kern_p[0];
    const int D  = C_ * (H_ / k) * (W_ / k);
    const int Np = N_ * D;

    const float* mu_a = ws;
    const float* va   = ws + (size_t)Np;
    const float* mu_b = ws + (size_t)2 * Np;
    const float* vb   = ws + (size_t)3 * Np;
    float* partials   = ws + (size_t)4 * Np;

    // ---- decode block -> (tile, chunk), R5 natural order ----
    const int c = blockIdx.x & (DCHUNKS - 1);
    const int t = blockIdx.x >> 4;           // DCHUNKS == 16
    int set, it, jt;
    if (t >= 2 * TRI_TILES) {
        set = 2;
        const int tt = t - 2 * TRI_TILES;
        it = tt >> 3;
        jt = tt & 7;
    } else {
        set = (t >= TRI_TILES) ? 1 : 0;
        const int tt = set ? (t - TRI_TILES) : t;
        int g = 0, cum = 0;
        while (cum + (g >> 1) + 1 <= tt) { cum += (g >> 1) + 1; ++g; }
        it = g;
        jt = tt - cum;
    }
    const int i0 = it * 4, j0 = jt * 8;

    const float *mu1, *v1, *mu2, *v2;
    if (set == 0)      { mu1 = mu2 = mu_a; v1 = v2 = va; }
    else if (set == 1) { mu1 = mu2 = mu_b; v1 = v2 = vb; }
    else               { mu1 = mu_a; v1 = va; mu2 = mu_b; v2 = vb; }

    // Uniform-weight tiles: all of set 2 (w=-2) and tri tiles strictly below
    // the diagonal, jt < it>>1 (w=2). Mixed tiles (jt == it>>1): 32 of 272.
    const bool uniform = (set == 2) || (jt < (it >> 1));
    const float wU = (set == 2) ? -2.0f : 2.0f;

    float tot = 0.0f;

    if (D == 16384) {
        // Fast path: chunk = 1024 elems = 256 threads x 1 float4.
        const int base = (c << 10) + ((int)threadIdx.x << 2);
        // i-state: 4 rows x {mu,var'} x {lo,hi} halves = 32 VGPR.
        f32x2 imlo[4], imhi[4], ivlo[4], ivhi[4];
        #pragma unroll
        for (int ir = 0; ir < 4; ++ir) {
            const float4 m4 = *(const float4*)(mu1 + (size_t)(i0 + ir) * 16384 + base);
            const float4 v4 = *(const float4*)(v1  + (size_t)(i0 + ir) * 16384 + base);
            imlo[ir].x = m4.x; imlo[ir].y = m4.y; imhi[ir].x = m4.z; imhi[ir].y = m4.w;
            ivlo[ir].x = v4.x; ivlo[ir].y = v4.y; ivhi[ir].x = v4.z; ivhi[ir].y = v4.w;
        }
        if (uniform) {
            // One packed accumulator per i-row (8 regs); weight applied once.
            f32x2 acc2[4];
            #pragma unroll
            for (int ir = 0; ir < 4; ++ir) { acc2[ir].x = 0.0f; acc2[ir].y = 0.0f; }
            #pragma unroll
            for (int j8 = 0; j8 < 8; ++j8) {
                const float4 jm = *(const float4*)(mu2 + (size_t)(j0 + j8) * 16384 + base);
                const float4 jv = *(const float4*)(v2  + (size_t)(j0 + j8) * 16384 + base);
                f32x2 jmlo, jmhi, jvlo, jvhi;
                jmlo.x = jm.x; jmlo.y = jm.y; jmhi.x = jm.z; jmhi.y = jm.w;
                jvlo.x = jv.x; jvlo.y = jv.y; jvhi.x = jv.z; jvhi.y = jv.w;
                #pragma unroll
                for (int ir = 0; ir < 4; ++ir) {
                    TERM2(acc2[ir], imlo[ir], ivlo[ir], jmlo, jvlo)
                    TERM2(acc2[ir], imhi[ir], ivhi[ir], jmhi, jvhi)
                }
            }
            const f32x2 s2 = (acc2[0] + acc2[1]) + (acc2[2] + acc2[3]);
            tot = wU * (s2.x + s2.y);
        } else {
            // Mixed tile (tri diagonal band): fold the 0/1/2 weight at the end
            // of each (ir, j8) — no persistent accumulator array.
            #pragma unroll
            for (int j8 = 0; j8 < 8; ++j8) {
                const float4 jm = *(const float4*)(mu2 + (size_t)(j0 + j8) * 16384 + base);
                const float4 jv = *(const float4*)(v2  + (size_t)(j0 + j8) * 16384 + base);
                f32x2 jmlo, jmhi, jvlo, jvhi;
                jmlo.x = jm.x; jmlo.y = jm.y; jmhi.x = jm.z; jmhi.y = jm.w;
                jvlo.x = jv.x; jvlo.y = jv.y; jvhi.x = jv.z; jvhi.y = jv.w;
                const int jj = j0 + j8;
                #pragma unroll
                for (int ir = 0; ir < 4; ++ir) {
                    f32x2 a; a.x = 0.0f; a.y = 0.0f;
                    TERM2(a, imlo[ir], ivlo[ir], jmlo, jvlo)
                    TERM2(a, imhi[ir], ivhi[ir], jmhi, jvhi)
                    const int ii = i0 + ir;
                    const float w = (jj > ii) ? 0.0f : (jj == ii) ? 1.0f : 2.0f;
                    tot = fmaf(w, a.x + a.y, tot);
                }
            }
        }
    } else {
        // Generic fallback: scalar, weight folded per (ir,j8), single scalar
        // accumulator (keeps fallback's register pressure from inflating the
        // kernel's VGPR allocation).
        const int cs = D / DCHUNKS;
        const int lo = c * cs, hi = lo + cs;
        for (int e = lo + (int)threadIdx.x; e < hi; e += 256) {
            #pragma unroll
            for (int j8 = 0; j8 < 8; ++j8) {
                const int jj = j0 + j8;
                const float mj = mu2[(size_t)jj * D + e];
                const float vj = v2 [(size_t)jj * D + e];
                #pragma unroll
                for (int ir = 0; ir < 4; ++ir) {
                    const int ii = i0 + ir;
                    const float w = (set == 2) ? -2.0f
                                  : (jj > ii) ? 0.0f : (jj == ii) ? 1.0f : 2.0f;
                    const float mi = mu1[(size_t)ii * D + e];
                    const float vi = v1 [(size_t)ii * D + e];
                    float v_  = vi + vj;
                    float rs_ = __builtin_amdgcn_rsqf(v_);
                    float d_  = mi - mj;
                    float t_  = d_ * rs_;
                    float e_  = __builtin_amdgcn_exp2f(-(t_ * t_));
                    tot = fmaf(w, e_ * rs_, tot);
                }
            }
        }
    }

    tot *= SQRT_2LN2;   // fold the var'-prescale correction once

    for (int off = 32; off > 0; off >>= 1)
        tot += __shfl_down(tot, off, 64);
    __shared__ float wsum[4];
    const int lane = threadIdx.x & 63;
    const int wid  = threadIdx.x >> 6;
    if (lane == 0) wsum[wid] = tot;
    __syncthreads();
    if (threadIdx.x == 0) {
        partials[blockIdx.x] = wsum[0] + wsum[1] + wsum[2] + wsum[3];
    }
}

// Single block: sum the PAIR_BLOCKS partials into out[0].
__global__ __launch_bounds__(256) void reduce_kernel(const float* __restrict__ ws,
                                                     const int* __restrict__ kern_p,
                                                     float* __restrict__ out) {
    const int k = kern_p[0];
    const int D  = C_ * (H_ / k) * (W_ / k);
    const int Np = N_ * D;
    const float* partials = ws + (size_t)4 * Np;

    float s = 0.0f;
    for (int p = threadIdx.x; p < PAIR_BLOCKS; p += 256) s += partials[p];
    for (int off = 32; off > 0; off >>= 1)
        s += __shfl_down(s, off, 64);
    __shared__ float wsum[4];
    const int lane = threadIdx.x & 63;
    const int wid  = threadIdx.x >> 6;
    if (lane == 0) wsum[wid] = s;
    __syncthreads();
    if (threadIdx.x == 0) out[0] = wsum[0] + wsum[1] + wsum[2] + wsum[3];
}

extern "C" void kernel_launch(void* const* d_in, const int* in_sizes, int n_in,
                              void* d_out, int out_size, void* d_ws, size_t ws_size,
                              hipStream_t stream) {
    const float* mu_a = (const float*)d_in[0];
    const float* lv_a = (const float*)d_in[1];
    const float* mu_b = (const float*)d_in[2];
    const float* lv_b = (const float*)d_in[3];
    const int*   kern = (const int*)d_in[4];
    float* out = (float*)d_out;
    float* ws  = (float*)d_ws;

    pool_kernel<<<4096, 256, 0, stream>>>(mu_a, lv_a, mu_b, lv_b, kern, ws);
    pair_kernel<<<PAIR_BLOCKS, 256, 0, stream>>>(ws, kern);
    reduce_kernel<<<1, 256, 0, stream>>>(ws, kern, out);
}